// Round 10
// baseline (390.500 us; speedup 1.0000x reference)
//
#include <hip/hip_runtime.h>
#include <hip/hip_bf16.h>
#include <math.h>

// Problem constants (fixed by setup_inputs)
#define M_TOTAL 6272   // B*P
#define N_CS    16384  // coreset rows
#define D_DIM   384
#define BATCH   8
#define P_PATCH 784
#define KNN     9

// MFMA GEMM tiling: 128x256 tile, 4 waves (2x2 of 64x128)
#define MTILES  (M_TOTAL / 128)  // 49
#define NTILES2 (N_CS / 256)     // 64 -> pvals[m][64]
#define NBLK    (M_TOTAL / 4)    // 1568 reduce blocks; 784=4*196 -> one batch/block
#define PBB     196              // partial entries per batch

typedef _Float16 half8 __attribute__((ext_vector_type(8)));
typedef float    floatx4 __attribute__((ext_vector_type(4)));

__device__ __forceinline__ unsigned long long shfl_xor_u64(unsigned long long v, int mk) {
    int lo = __shfl_xor((int)(unsigned)v, mk, 64);
    int hi = __shfl_xor((int)(unsigned)(v >> 32), mk, 64);
    return ((unsigned long long)(unsigned)hi << 32) | (unsigned)lo;
}

// ---------------- convert fp32->f16, fused cs+emb (wave per row) ----------
__global__ void convert_all_kernel(const float* __restrict__ emb,
                                   const float* __restrict__ cs,
                                   _Float16* __restrict__ embh,
                                   _Float16* __restrict__ csh,
                                   float* __restrict__ cnorm) {
    int w = threadIdx.x >> 6, lane = threadIdx.x & 63;
    int row = blockIdx.x * 4 + w;
    if (row >= N_CS + M_TOTAL) return;
    bool is_cs = row < N_CS;
    const float* r = (is_cs ? cs + (size_t)row * D_DIM
                            : emb + (size_t)(row - N_CS) * D_DIM) + lane * 6;
    float2 a = *(const float2*)r;
    float2 b = *(const float2*)(r + 2);
    float2 c = *(const float2*)(r + 4);
    union { _Float16 h[2]; unsigned u; } p0, p1, p2;
    p0.h[0] = (_Float16)a.x; p0.h[1] = (_Float16)a.y;
    p1.h[0] = (_Float16)b.x; p1.h[1] = (_Float16)b.y;
    p2.h[0] = (_Float16)c.x; p2.h[1] = (_Float16)c.y;
    unsigned* dst = (unsigned*)(is_cs ? csh + (size_t)row * D_DIM
                                      : embh + (size_t)(row - N_CS) * D_DIM) + lane * 3;
    dst[0] = p0.u; dst[1] = p1.u; dst[2] = p2.u;
    if (is_cs) {
        float s = a.x * a.x + a.y * a.y + b.x * b.x + b.y * b.y + c.x * c.x + c.y * c.y;
#pragma unroll
        for (int mk = 1; mk <= 32; mk <<= 1) s += __shfl_xor(s, mk, 64);
        if (lane == 0) cnorm[row] = s;
    }
}

// --------------------------------------------- MFMA GEMM + min/argmin ----
// R10 structural change: NO LDS STAGING. For mfma_16x16x32_f16 a lane's
// A- and B-fragments are 8 CONSECUTIVE k of one row — row-major operands
// need no transpose, so fragments load directly global->VGPR as
// global_load_dwordx4 (4 lanes cover a full 64B line). Zero barriers in
// the K-loop; waves fully independent; XCD remap keeps the 1.5 MB B-set
// L2-resident (R7: FETCH 191->25 MB). 2-stage rotating register pipeline
// bounds in-flight loads. LDS only for the 2 KB epilogue scratch.
// __launch_bounds__(256,2): DO NOT raise (R6: VGPR squeeze -> acc spill).
__global__ __launch_bounds__(256, 2) void mindist_mfma_kernel(
    const _Float16* __restrict__ embh, const _Float16* __restrict__ csh,
    const float* __restrict__ cnorm,
    float* __restrict__ pvals, int* __restrict__ pidx) {
    __shared__ float smv[256];          // [128][2]
    __shared__ int   smi[256];

    const int b    = blockIdx.x;
    const int bx   = b >> 6;                               // 0..48
    const int by   = ((b & 7) << 3) | ((b >> 3) & 7);      // 0..63 (XCD-major)
    const int tid  = threadIdx.x;
    const int lane = tid & 63;
    const int w    = tid >> 6;
    const int wr   = w >> 1, wc = w & 1;
    const int row0  = bx * 128;
    const int cbase = by * 256;
    const int q   = lane >> 4;
    const int cl  = lane & 15;

    floatx4 acc[4][8];
#pragma unroll
    for (int mi = 0; mi < 4; ++mi)
#pragma unroll
        for (int nj = 0; nj < 8; ++nj) acc[mi][nj] = (floatx4){0.f, 0.f, 0.f, 0.f};

    float cn_l[8];
#pragma unroll
    for (int nj = 0; nj < 8; ++nj)
        cn_l[nj] = cnorm[cbase + wc * 128 + nj * 16 + cl];

    // per-lane fragment row pointers (k-offset q*8 folded in; chunk adds kk)
    const _Float16* pa[4];
    const _Float16* pb[8];
#pragma unroll
    for (int mi = 0; mi < 4; ++mi)
        pa[mi] = embh + (size_t)(row0 + wr * 64 + mi * 16 + cl) * D_DIM + q * 8;
#pragma unroll
    for (int nj = 0; nj < 8; ++nj)
        pb[nj] = csh + (size_t)(cbase + wc * 128 + nj * 16 + cl) * D_DIM + q * 8;

#define LOADF(AF, BF, KK)                                                     \
    {                                                                         \
        _Pragma("unroll")                                                     \
        for (int mi = 0; mi < 4; ++mi) AF[mi] = *(const half8*)(pa[mi] + (KK)); \
        _Pragma("unroll")                                                     \
        for (int nj = 0; nj < 8; ++nj) BF[nj] = *(const half8*)(pb[nj] + (KK)); \
    }
#define MFMAF(AF, BF)                                                         \
    {                                                                         \
        _Pragma("unroll")                                                     \
        for (int mi = 0; mi < 4; ++mi)                                        \
            _Pragma("unroll")                                                 \
            for (int nj = 0; nj < 8; ++nj)                                    \
                acc[mi][nj] = __builtin_amdgcn_mfma_f32_16x16x32_f16(         \
                    AF[mi], BF[nj], acc[mi][nj], 0, 0, 0);                    \
    }

    // 12 chunks of K=32, 2-stage rotating pipeline (no barriers at all)
    half8 a0[4], b0[8], a1[4], b1[8];
    LOADF(a0, b0, 0);
#pragma unroll 1
    for (int jj = 0; jj < 5; ++jj) {
        int kk = jj * 64;
        LOADF(a1, b1, kk + 32);
        MFMAF(a0, b0);
        LOADF(a0, b0, kk + 64);
        MFMAF(a1, b1);
    }
    LOADF(a1, b1, 352);
    MFMAF(a0, b0);   // chunk 320
    MFMAF(a1, b1);   // chunk 352
#undef LOADF
#undef MFMAF

    // epilogue: per-row min/argmin over the 256-wide tile
#pragma unroll
    for (int mi = 0; mi < 4; ++mi) {
#pragma unroll
        for (int r = 0; r < 4; ++r) {
            float v = 3.4e38f; int idx = 0x7fffffff;
#pragma unroll
            for (int nj = 0; nj < 8; ++nj) {   // ascending col per lane, strict <
                float d = cn_l[nj] - 2.f * acc[mi][nj][r];
                int   c = cbase + wc * 128 + nj * 16 + cl;
                if (d < v) { v = d; idx = c; }
            }
#pragma unroll
            for (int mk = 1; mk <= 8; mk <<= 1) {
                float v2 = __shfl_xor(v, mk, 64);
                int   i2 = __shfl_xor(idx, mk, 64);
                if (v2 < v || (v2 == v && i2 < idx)) { v = v2; idx = i2; }
            }
            if (cl == 0) {
                int rl = wr * 64 + mi * 16 + q * 4 + r;
                smv[rl * 2 + wc] = v;
                smi[rl * 2 + wc] = idx;
            }
        }
    }
    __syncthreads();
    if (tid < 128) {
        float v = smv[tid * 2];      int i = smi[tid * 2];
        float v1 = smv[tid * 2 + 1]; int i1 = smi[tid * 2 + 1];
        if (v1 < v) { v = v1; i = i1; }   // wc0 indices always < wc1 indices
        pvals[(size_t)(row0 + tid) * NTILES2 + by] = v;
        pidx[(size_t)(row0 + tid) * NTILES2 + by]  = i;
    }
}

// ---- partial-min reduce + EXACT fp32 rescore + block-level argmax -------
// partial[block] = max over the block's 4 rows of (score_bits<<32)|(~patch):
// NO atomics (R7: 1568 device atomicMax on one 64B line bounced across
// XCDs, ~65 us serialization). dnn/top9 re-scan the 12.5 KB array instead.
__global__ void reduce_rescore_kernel(const float* __restrict__ pvals,
                                      const int* __restrict__ pidx,
                                      const float* __restrict__ emb,
                                      const float* __restrict__ cs,
                                      int* __restrict__ loc,
                                      unsigned long long* __restrict__ partial) {
    __shared__ unsigned long long keys[4];
    int w = threadIdx.x >> 6, lane = threadIdx.x & 63;
    int m = blockIdx.x * 4 + w;
    float v = pvals[(size_t)m * NTILES2 + lane];
    int   i = pidx[(size_t)m * NTILES2 + lane];
#pragma unroll
    for (int mk = 1; mk <= 32; mk <<= 1) {
        float v2 = __shfl_xor(v, mk, 64);
        int   i2 = __shfl_xor(i, mk, 64);
        if (v2 < v || (v2 == v && i2 < i)) { v = v2; i = i2; }
    }
    // exact fp32 distance to the selected coreset row
    const float* a = emb + (size_t)m * D_DIM;
    const float* bp = cs + (size_t)i * D_DIM;
    float s = 0.f;
#pragma unroll
    for (int t = 0; t < D_DIM / 64; ++t) {
        float d = a[lane + t * 64] - bp[lane + t * 64];
        s += d * d;
    }
#pragma unroll
    for (int mk = 1; mk <= 32; mk <<= 1) s += __shfl_xor(s, mk, 64);
    if (lane == 0) {
        float sc = sqrtf(s);
        loc[m] = i;
        int p = m % P_PATCH;
        keys[w] = ((unsigned long long)__float_as_uint(sc) << 32) |
                  (unsigned)(0x7fffffff - p);
    }
    __syncthreads();
    if (threadIdx.x == 0) {
        unsigned long long k = keys[0];
        if (keys[1] > k) k = keys[1];
        if (keys[2] > k) k = keys[2];
        if (keys[3] > k) k = keys[3];
        partial[blockIdx.x] = k;
    }
}

// -------------------- d_nn: 8 queries x 16384 coreset (coalesced GEMV) ----
__global__ void dnn_kernel(const float* __restrict__ cs,
                           const float* __restrict__ cnorm,
                           const unsigned long long* __restrict__ partial,
                           const int* __restrict__ loc,
                           float* __restrict__ dmat) {
    __shared__ int bnnS[BATCH];
    {   // per-block argmax recompute: 32 lanes per batch over 196 entries
        int bb = threadIdx.x >> 5, l32 = threadIdx.x & 31;
        unsigned long long best = 0ull;
        for (int j = l32; j < PBB; j += 32) {
            unsigned long long k = partial[bb * PBB + j];
            if (k > best) best = k;
        }
#pragma unroll
        for (int mk = 1; mk <= 16; mk <<= 1) {
            unsigned long long o = shfl_xor_u64(best, mk);
            if (o > best) best = o;
        }
        if (l32 == 0) {
            int p = 0x7fffffff - (unsigned)(best & 0xffffffffull);
            bnnS[bb] = loc[bb * P_PATCH + p];
        }
    }
    __syncthreads();

    int lane = threadIdx.x & 63;
    int gw = (blockIdx.x * 256 + threadIdx.x) >> 6;  // 0..1023
    float qv[BATCH][6];
#pragma unroll
    for (int b = 0; b < BATCH; ++b) {
        const float* qr = cs + (size_t)bnnS[b] * D_DIM + lane * 6;
#pragma unroll
        for (int j = 0; j < 6; ++j) qv[b][j] = qr[j];
    }
    for (int n = gw; n < N_CS; n += 1024) {
        const float* r = cs + (size_t)n * D_DIM + lane * 6;
        float x[6];
#pragma unroll
        for (int j = 0; j < 6; ++j) x[j] = r[j];
        float s[BATCH];
#pragma unroll
        for (int b = 0; b < BATCH; ++b) {
            float t = 0.f;
#pragma unroll
            for (int j = 0; j < 6; ++j) t += x[j] * qv[b][j];
            s[b] = t;
        }
#pragma unroll
        for (int b = 0; b < BATCH; ++b)
#pragma unroll
            for (int mk = 1; mk <= 32; mk <<= 1) s[b] += __shfl_xor(s[b], mk, 64);
        if (lane < BATCH) {
            float sv = s[0];
#pragma unroll
            for (int b = 1; b < BATCH; ++b) sv = (lane == b) ? s[b] : sv;
            dmat[(size_t)lane * N_CS + n] = cnorm[n] - 2.f * sv;  // -qnorm shift: order-safe
        }
    }
}

// ----------------------- top-9 merge + exact dsup + softmax weighting ----
__device__ inline void merge9(float* av, int* ai, const float* bv, const int* bi) {
    float mv[KNN]; int mi[KNN];
    int x = 0, y = 0;
#pragma unroll
    for (int k = 0; k < KNN; ++k) {
        bool ta = (av[x] < bv[y]) || (av[x] == bv[y] && ai[x] < bi[y]);
        if (ta) { mv[k] = av[x]; mi[k] = ai[x]; ++x; }
        else    { mv[k] = bv[y]; mi[k] = bi[y]; ++y; }
    }
#pragma unroll
    for (int k = 0; k < KNN; ++k) { av[k] = mv[k]; ai[k] = mi[k]; }
}

__global__ void top9_final_kernel(const float* __restrict__ dmat,
                                  const float* __restrict__ emb,
                                  const float* __restrict__ cs,
                                  const unsigned long long* __restrict__ partial,
                                  float* __restrict__ out) {
    int b = blockIdx.x;
    int tid = threadIdx.x;  // 512
    __shared__ float lv[512][KNN];
    __shared__ int   li[512][KNN];
    __shared__ float mf[D_DIM];
    __shared__ float dsup[KNN];
    __shared__ float bscoreS;
    __shared__ int   bpatchS;

    if (tid < 64) {  // argmax recompute for this batch
        unsigned long long best = 0ull;
        for (int j = tid; j < PBB; j += 64) {
            unsigned long long k = partial[b * PBB + j];
            if (k > best) best = k;
        }
#pragma unroll
        for (int mk = 1; mk <= 32; mk <<= 1) {
            unsigned long long o = shfl_xor_u64(best, mk);
            if (o > best) best = o;
        }
        if (tid == 0) {
            bpatchS = 0x7fffffff - (unsigned)(best & 0xffffffffull);
            bscoreS = __uint_as_float((unsigned)(best >> 32));
        }
    }
    __syncthreads();
    int mp = bpatchS;
    const float* frow = emb + (size_t)(b * P_PATCH + mp) * D_DIM;
    for (int i = tid; i < D_DIM; i += 512) mf[i] = frow[i];

    float tv[KNN]; int ti[KNN];
#pragma unroll
    for (int k = 0; k < KNN; ++k) { tv[k] = 3.4e38f; ti[k] = 0x7fffffff; }
    for (int n = tid; n < N_CS; n += 512) {   // ascending n per thread
        float d = dmat[(size_t)b * N_CS + n];
        if (d < tv[KNN - 1] || (d == tv[KNN - 1] && n < ti[KNN - 1])) {
            tv[KNN - 1] = d; ti[KNN - 1] = n;
#pragma unroll
            for (int k = KNN - 1; k > 0; --k) {
                if (tv[k] < tv[k - 1] || (tv[k] == tv[k - 1] && ti[k] < ti[k - 1])) {
                    float fv = tv[k]; tv[k] = tv[k - 1]; tv[k - 1] = fv;
                    int   iv = ti[k]; ti[k] = ti[k - 1]; ti[k - 1] = iv;
                }
            }
        }
    }
#pragma unroll
    for (int k = 0; k < KNN; ++k) { lv[tid][k] = tv[k]; li[tid][k] = ti[k]; }
    __syncthreads();
    for (int off = 256; off > 0; off >>= 1) {
        if (tid < off) {
            float av[KNN]; int ai[KNN]; float bv2[KNN]; int bi2[KNN];
#pragma unroll
            for (int k = 0; k < KNN; ++k) {
                av[k]  = lv[tid][k];        ai[k]  = li[tid][k];
                bv2[k] = lv[tid + off][k];  bi2[k] = li[tid + off][k];
            }
            merge9(av, ai, bv2, bi2);
#pragma unroll
            for (int k = 0; k < KNN; ++k) { lv[tid][k] = av[k]; li[tid][k] = ai[k]; }
        }
        __syncthreads();
    }
    // exact fp32 distances to the 9 support rows: 32 lanes per neighbor
    {
        int k      = tid >> 5;   // 0..15
        int lane32 = tid & 31;
        if (k < KNN) {
            int idx = li[0][k];
            const float* r = cs + (size_t)idx * D_DIM;
            float s = 0.f;
            for (int i = lane32; i < D_DIM; i += 32) {
                float df = mf[i] - r[i];
                s += df * df;
            }
#pragma unroll
            for (int mk = 1; mk <= 16; mk <<= 1) s += __shfl_xor(s, mk, 64);
            if (lane32 == 0) dsup[k] = sqrtf(fmaxf(s, 0.f));
        }
    }
    __syncthreads();
    if (tid == 0) {
        float mx = dsup[0];
        for (int k = 1; k < KNN; ++k) mx = fmaxf(mx, dsup[k]);
        float sum = 0.f, e0 = 0.f;
        for (int k = 0; k < KNN; ++k) {
            float e = expf(dsup[k] - mx);
            sum += e;
            if (k == 0) e0 = e;
        }
        out[b] = (1.f - e0 / sum) * bscoreS;
    }
}

// ------------------------------------------------------------- launcher ----
extern "C" void kernel_launch(void* const* d_in, const int* in_sizes, int n_in,
                              void* d_out, int out_size, void* d_ws, size_t ws_size,
                              hipStream_t stream) {
    (void)in_sizes; (void)n_in; (void)out_size; (void)ws_size;
    const float* emb = (const float*)d_in[0];
    const float* cs  = (const float*)d_in[1];
    float* out = (float*)d_out;

    // workspace layout
    char* p = (char*)d_ws;
    float* cnorm  = (float*)p;  p += (size_t)N_CS * 4;                     // 64 KB
    float* pvals  = (float*)p;  p += (size_t)M_TOTAL * NTILES2 * 4;        // 1.6 MB
    int*   pidx   = (int*)p;    p += (size_t)M_TOTAL * NTILES2 * 4;        // 1.6 MB
    int*   loc    = (int*)p;    p += (size_t)M_TOTAL * 4;
    p = (char*)(((size_t)p + 7) & ~(size_t)7);
    unsigned long long* partial = (unsigned long long*)p; p += NBLK * 8;   // 12.5 KB
    float* dmat   = (float*)p;  p += (size_t)BATCH * N_CS * 4;             // 512 KB
    p = (char*)(((size_t)p + 15) & ~(size_t)15);
    _Float16* embh = (_Float16*)p; p += (size_t)M_TOTAL * D_DIM * 2;       // 4.8 MB
    _Float16* csh  = (_Float16*)p; p += (size_t)N_CS * D_DIM * 2;          // 12.6 MB

    {
        int rows = N_CS + M_TOTAL;
        convert_all_kernel<<<(rows + 3) / 4, 256, 0, stream>>>(emb, cs, embh, csh, cnorm);
    }
    mindist_mfma_kernel<<<MTILES * NTILES2, 256, 0, stream>>>(embh, csh, cnorm,
                                                              pvals, pidx);
    reduce_rescore_kernel<<<NBLK, 256, 0, stream>>>(pvals, pidx, emb, cs, loc, partial);
    dnn_kernel<<<256, 256, 0, stream>>>(cs, cnorm, partial, loc, dmat);
    top9_final_kernel<<<BATCH, 512, 0, stream>>>(dmat, emb, cs, partial, out);
}